// Round 6
// baseline (209.875 us; speedup 1.0000x reference)
//
#include <hip/hip_runtime.h>

// Problem constants
#define M_ROWS 8192            // B*L = 4*2048
#define N_DIM  1024            // D
#define K3     3072            // 3*D
#define KD     16              // K_DIM
#define BM     256
#define BN     128
#define BK     128
#define NKT    24              // K3 / BK
#define LDS_A  (BM * BK)       // 32768 ushorts = 64 KB per buffer; 2 buffers = 128 KB

typedef __bf16 bf16x8 __attribute__((ext_vector_type(8)));
typedef float  f32x4  __attribute__((ext_vector_type(4)));

__device__ __forceinline__ unsigned short f2bf(float f) {
  return __builtin_bit_cast(unsigned short, (__bf16)f);
}
__device__ __forceinline__ float bf2f(unsigned short u) {
  return __builtin_bit_cast(float, (unsigned int)u << 16);
}
__device__ __forceinline__ ushort4 pack4(float4 f) {
  ushort4 o; o.x = f2bf(f.x); o.y = f2bf(f.y); o.z = f2bf(f.z); o.w = f2bf(f.w);
  return o;
}

__device__ __forceinline__ void async16(const void* g, void* l) {
  __builtin_amdgcn_global_load_lds(
      (const __attribute__((address_space(1))) unsigned int*)g,
      (__attribute__((address_space(3))) unsigned int*)l, 16, 0, 0);
}

// Fused prep:
//  blocks [0, 8192):       convert x,y,z -> Ib[8192][3072] bf16 (cols: x|y|z) and P = bf16(x*y)
//  blocks [8192, 11264):   Wsum[d][c] = bf16(sum_k W[d*16+k][c])  (1024x3072)
//  blocks [11264, 11268):  bsum[d] = sum_k b[d*16+k]  (fp32)
__global__ __launch_bounds__(256) void prep_kernel(
    const float4* __restrict__ x, const float4* __restrict__ y, const float4* __restrict__ z,
    const float* __restrict__ W, const float* __restrict__ b,
    ushort4* __restrict__ Ib4, ushort4* __restrict__ P4,
    ushort4* __restrict__ Wsum4, float* __restrict__ bsum)
{
  int bid = blockIdx.x;
  int tid = threadIdx.x;
  if (bid < 8192) {
    int i = bid * 256 + tid;          // float4 index over [8192][256]
    int m = bid;
    int c4 = tid;
    float4 fx = x[i], fy = y[i], fz = z[i];
    size_t rb = (size_t)m * 768;
    Ib4[rb + c4]       = pack4(fx);
    Ib4[rb + 256 + c4] = pack4(fy);
    Ib4[rb + 512 + c4] = pack4(fz);
    float4 p; p.x = fx.x * fy.x; p.y = fx.y * fy.y; p.z = fx.z * fy.z; p.w = fx.w * fy.w;
    P4[i] = pack4(p);
  } else if (bid < 11264) {
    int g  = (bid - 8192) * 256 + tid;   // 0 .. 786431 float4 cols
    int d  = g / 768;
    int cq = g - d * 768;
    const float4* wrow = (const float4*)(W + (size_t)d * (KD * K3));
    float sx = 0.f, sy = 0.f, sz = 0.f, sw = 0.f;
    #pragma unroll
    for (int k = 0; k < KD; ++k) {
      float4 t = wrow[(size_t)k * (K3 / 4) + cq];
      sx += t.x; sy += t.y; sz += t.z; sw += t.w;
    }
    ushort4 o; o.x = f2bf(sx); o.y = f2bf(sy); o.z = f2bf(sz); o.w = f2bf(sw);
    Wsum4[g] = o;
  } else {
    int d = (bid - 11264) * 256 + tid;
    if (d < N_DIM) {
      float s = 0.f;
      #pragma unroll
      for (int k = 0; k < KD; ++k) s += b[d * KD + k];
      bsum[d] = s;
    }
  }
}

// GEMM C[m,n] = sum_k Ib[m,k]*Wsum[n,k]; out[m,n] = (C + bsum[n]) * P[m,n]
// BM=256 x BN=128, BK=128. A in LDS (2-deep, chunk-XOR swizzled, global_load_lds);
// B (Wsum, L2-resident) loaded DIRECTLY to VGPRs, double-buffered one K-tile ahead
// in E(kk=0,1)/L(kk=2,3) halves. 8 waves (4Mx2N, 64x64 each). One counted
// vmcnt(8)+barrier per K-tile; L-half stays in flight across the barrier.
__global__ __launch_bounds__(512, 2) void gemm_ep_kernel(
    const unsigned short* __restrict__ Ib, const unsigned short* __restrict__ Wsum,
    const float* __restrict__ bsum, const unsigned short* __restrict__ P,
    float* __restrict__ out)
{
  extern __shared__ unsigned short lds[];   // 2 * LDS_A ushorts = 128 KB

  // XCD-aware bijective swizzle: 256 blocks, 8 XCDs, 32 blocks each.
  int bid = blockIdx.x;
  int swz = (bid & 7) * 32 + (bid >> 3);
  int mt = swz >> 3;          // 0..31
  int nt = swz & 7;           // 0..7
  int m0 = mt * BM, n0 = nt * BN;

  int tid  = threadIdx.x;     // 0..511
  int lane = tid & 63;
  int wid  = tid >> 6;        // 0..7
  int wr = wid >> 1, wc = wid & 1;   // 4x2 wave grid, each wave 64x64 out
  int fr = lane & 15;
  int hi = lane >> 4;                // 0..3

  // A staging: 64KB/tile = 8 rounds x (512 thr x 16B); rows of 256B (16 chunks)
  int row0 = tid >> 4;               // 0..31 (round r adds 32)
  int ch0  = tid & 15;               // 16B chunk within row
  int sc   = (ch0 ^ (row0 & 15)) << 3;   // pre-swizzled source chunk (ushort units)
  int dofs = tid * 16;               // byte offset within an 8KB round

  const unsigned short* Abase = Ib + (size_t)m0 * K3;

  // B row bases (ushort index into Wsum), one per j
  int bb[4];
  #pragma unroll
  for (int j = 0; j < 4; ++j)
    bb[j] = (n0 + wc * 64 + j * 16 + fr) * K3 + hi * 8;

  f32x4 acc[4][4];
  #pragma unroll
  for (int i = 0; i < 4; ++i)
    #pragma unroll
    for (int j = 0; j < 4; ++j)
      acc[i][j] = f32x4{0.f, 0.f, 0.f, 0.f};

  // stage 4 of 8 A-rounds of K-tile t into buffer slot
  auto STAGE_A4 = [&](int slot, int t, int rlo) {
    char* dst = (char*)lds + slot * (LDS_A * 2);
    int k0 = t * BK;
    #pragma unroll
    for (int r = rlo; r < rlo + 4; ++r)
      async16(Abase + (size_t)(row0 + r * 32) * K3 + k0 + sc, dst + dofs + r * 8192);
  };
  // load 8 B-frags (2 kk x 4 j) of K-tile t starting at kk=kkb
  auto LOADB8 = [&](int t, int kkb, bf16x8* dst) {
    int k0 = t * BK + kkb * 32;
    #pragma unroll
    for (int q = 0; q < 8; ++q) {
      int kk = q >> 2, j = q & 3;
      dst[q] = *(const bf16x8*)&Wsum[(size_t)(bb[j] + k0 + kk * 32)];
    }
  };
  // ds_read the 4 A-frags for sub-k kk (phys chunk = (kk*4+hi) ^ fr)
  auto LOADA = [&](const unsigned short* pA, int kk, bf16x8* a) {
    #pragma unroll
    for (int i = 0; i < 4; ++i) {
      int R = wr * 64 + i * 16 + fr;
      a[i] = *(const bf16x8*)&pA[R * BK + ((((kk << 2) + hi) ^ fr) << 3)];
    }
  };
  auto MF = [&](bf16x8* a, bf16x8* b4) {
    __builtin_amdgcn_s_setprio(1);
    #pragma unroll
    for (int i = 0; i < 4; ++i)
      #pragma unroll
      for (int j = 0; j < 4; ++j)
        acc[i][j] = __builtin_amdgcn_mfma_f32_16x16x32_bf16(a[i], b4[j], acc[i][j], 0, 0, 0);
    __builtin_amdgcn_s_setprio(0);
  };

  bf16x8 bE0[8], bL0[8], bE1[8], bL1[8];

  // K-tile body. VMEM issue order per tile: [E(t+1), A(t+1) r0-3] ... [A(t+1) r4-7] | pin | [L(t+1)]
  // so end-of-tile vmcnt(8) leaves exactly L(t+1) in flight.
  auto TILE = [&](int t, int slot, bf16x8* bEc, bf16x8* bLc, bf16x8* bEn, bf16x8* bLn, bool st) {
    const unsigned short* pA = lds + slot * LDS_A;
    bf16x8 a[4];
    // ph0 (kk=0)
    LOADA(pA, 0, a);
    if (st) { LOADB8(t + 1, 0, bEn); STAGE_A4(slot ^ 1, t + 1, 0); }
    MF(a, bEc + 0);
    // ph1 (kk=1)
    LOADA(pA, 1, a);
    MF(a, bEc + 4);
    __builtin_amdgcn_s_barrier();          // mid-tile wave alignment
    // ph2 (kk=2)
    LOADA(pA, 2, a);
    if (st) {
      STAGE_A4(slot ^ 1, t + 1, 4);
      // pin VMEM order: all E/A issues precede L issues (vmcnt counting depends on it);
      // mask lets VALU/MFMA/DS flow across, blocks VMEM reordering.
      __builtin_amdgcn_sched_barrier(0x38F);
      LOADB8(t + 1, 2, bLn);
    }
    MF(a, bLc + 0);
    // ph3 (kk=3)
    LOADA(pA, 3, a);
    MF(a, bLc + 4);
    // end of tile: A(t+1) fully in LDS, E(t+1) in regs; L(t+1) (8 loads) stays in flight
    if (st) asm volatile("s_waitcnt vmcnt(8)" ::: "memory");
    else    asm volatile("s_waitcnt vmcnt(0)" ::: "memory");
    __builtin_amdgcn_s_barrier();
  };

  // prologue: tile 0 — order [E(0) x8, A(0) x8] | pin | [L(0) x8]; vmcnt(8) leaves L(0)
  LOADB8(0, 0, bE0);
  STAGE_A4(0, 0, 0);
  STAGE_A4(0, 0, 4);
  __builtin_amdgcn_sched_barrier(0x38F);
  LOADB8(0, 2, bL0);
  asm volatile("s_waitcnt vmcnt(8)" ::: "memory");
  __builtin_amdgcn_s_barrier();

  #pragma unroll 1
  for (int th = 0; th < NKT; th += 2) {
    TILE(th,     0, bE0, bL0, bE1, bL1, true);
    TILE(th + 1, 1, bE1, bL1, bE0, bL0, th + 2 < NKT);
  }

  // Epilogue: C/D layout col = lane&15, row = (lane>>4)*4 + reg  [verified m89/m91]
  #pragma unroll
  for (int i = 0; i < 4; ++i) {
    #pragma unroll
    for (int j = 0; j < 4; ++j) {
      int n = n0 + wc * 64 + j * 16 + fr;
      float bs = bsum[n];
      #pragma unroll
      for (int r = 0; r < 4; ++r) {
        int m = m0 + wr * 64 + i * 16 + hi * 4 + r;
        size_t idx = (size_t)m * N_DIM + n;
        out[idx] = (acc[i][j][r] + bs) * bf2f(P[idx]);
      }
    }
  }
}

extern "C" void kernel_launch(void* const* d_in, const int* in_sizes, int n_in,
                              void* d_out, int out_size, void* d_ws, size_t ws_size,
                              hipStream_t stream) {
  const float* x = (const float*)d_in[0];
  const float* y = (const float*)d_in[1];
  const float* z = (const float*)d_in[2];
  const float* W = (const float*)d_in[3];
  const float* b = (const float*)d_in[4];
  float* out = (float*)d_out;

  // ws layout: Ib bf16 [8192*3072]; Wsum bf16 [1024*3072]; P bf16 [8192*1024]; bsum f32[1024]
  unsigned short* Ib   = (unsigned short*)d_ws;
  unsigned short* Wsum = Ib + (size_t)M_ROWS * K3;
  unsigned short* P    = Wsum + (size_t)N_DIM * K3;
  float*          bsum = (float*)(P + (size_t)M_ROWS * N_DIM);

  // 1) fused prep: convert (8192 blocks) + reduce_w (3072) + reduce_b (4)
  prep_kernel<<<11268, 256, 0, stream>>>(
      (const float4*)x, (const float4*)y, (const float4*)z, W, b,
      (ushort4*)Ib, (ushort4*)P, (ushort4*)Wsum, bsum);

  // 2) GEMM + epilogue: 32 x 8 tiles of 256x128, 128 KB dynamic LDS
  gemm_ep_kernel<<<256, 512, 2 * LDS_A * sizeof(unsigned short), stream>>>(
      Ib, Wsum, bsum, P, out);
}

// Round 7
// 138.308 us; speedup vs baseline: 1.5174x; 1.5174x over previous
//
#include <hip/hip_runtime.h>

// Problem constants
#define M_ROWS 8192            // B*L = 4*2048
#define N_DIM  1024            // D
#define K3     3072            // 3*D
#define KD     16              // K_DIM
#define NKT    48              // K3 / BK
#define BM     256
#define BN     128
#define BK     64
#define LDS_A  (BM * BK)       // 16384 ushorts = 32 KB
#define LDS_B  (BN * BK)       // 8192 ushorts  = 16 KB
#define LDS_TILE (LDS_A + LDS_B)  // 24576 ushorts = 48 KB; 3 buffers = 144 KB

typedef __bf16 bf16x8 __attribute__((ext_vector_type(8)));
typedef float  f32x4  __attribute__((ext_vector_type(4)));

__device__ __forceinline__ unsigned short f2bf(float f) {
  return __builtin_bit_cast(unsigned short, (__bf16)f);
}
__device__ __forceinline__ float bf2f(unsigned short u) {
  return __builtin_bit_cast(float, (unsigned int)u << 16);
}
__device__ __forceinline__ ushort4 pack4(float4 f) {
  ushort4 o; o.x = f2bf(f.x); o.y = f2bf(f.y); o.z = f2bf(f.z); o.w = f2bf(f.w);
  return o;
}

__device__ __forceinline__ void async16(const void* g, void* l) {
  __builtin_amdgcn_global_load_lds(
      (const __attribute__((address_space(1))) unsigned int*)g,
      (__attribute__((address_space(3))) unsigned int*)l, 16, 0, 0);
}

// Fused prep:
//  blocks [0, 8192):       convert x,y,z -> Ib[8192][3072] bf16 (cols: x|y|z) and P = bf16(x*y)
//  blocks [8192, 11264):   Wsum[d][c] = bf16(sum_k W[d*16+k][c])  (1024x3072)
//  blocks [11264, 11268):  bsum[d] = sum_k b[d*16+k]  (fp32)
__global__ __launch_bounds__(256) void prep_kernel(
    const float4* __restrict__ x, const float4* __restrict__ y, const float4* __restrict__ z,
    const float* __restrict__ W, const float* __restrict__ b,
    ushort4* __restrict__ Ib4, ushort4* __restrict__ P4,
    ushort4* __restrict__ Wsum4, float* __restrict__ bsum)
{
  int bid = blockIdx.x;
  int tid = threadIdx.x;
  if (bid < 8192) {
    int i = bid * 256 + tid;          // float4 index over [8192][256]
    int m = bid;
    int c4 = tid;
    float4 fx = x[i], fy = y[i], fz = z[i];
    size_t rb = (size_t)m * 768;
    Ib4[rb + c4]       = pack4(fx);
    Ib4[rb + 256 + c4] = pack4(fy);
    Ib4[rb + 512 + c4] = pack4(fz);
    float4 p; p.x = fx.x * fy.x; p.y = fx.y * fy.y; p.z = fx.z * fy.z; p.w = fx.w * fy.w;
    P4[i] = pack4(p);
  } else if (bid < 11264) {
    int g  = (bid - 8192) * 256 + tid;   // 0 .. 786431 float4 cols
    int d  = g / 768;
    int cq = g - d * 768;
    const float4* wrow = (const float4*)(W + (size_t)d * (KD * K3));
    float sx = 0.f, sy = 0.f, sz = 0.f, sw = 0.f;
    #pragma unroll
    for (int k = 0; k < KD; ++k) {
      float4 t = wrow[(size_t)k * (K3 / 4) + cq];
      sx += t.x; sy += t.y; sz += t.z; sw += t.w;
    }
    ushort4 o; o.x = f2bf(sx); o.y = f2bf(sy); o.z = f2bf(sz); o.w = f2bf(sw);
    Wsum4[g] = o;
  } else {
    int d = (bid - 11264) * 256 + tid;
    if (d < N_DIM) {
      float s = 0.f;
      #pragma unroll
      for (int k = 0; k < KD; ++k) s += b[d * KD + k];
      bsum[d] = s;
    }
  }
}

// GEMM C[m,n] = sum_k Ib[m,k]*Wsum[n,k]; out[m,n] = (C + bsum[n]) * P[m,n]
// BM=256 x BN=128, BK=64, 8 waves (4Mx2N, 64x64 each), 3-deep LDS pipeline.
// ONE barrier per K-tile: {16 ds_read || stage t+2} -> lgkm(8) -> 16 MFMA ->
// lgkm(0) -> 16 MFMA -> vmcnt(6) -> barrier.  Linear block->XCD mapping
// (nt == bid%8 == XCD) keeps each XCD's single B-panel L2-resident.
__global__ __launch_bounds__(512, 2) void gemm_ep_kernel(
    const unsigned short* __restrict__ Ib, const unsigned short* __restrict__ Wsum,
    const float* __restrict__ bsum, const unsigned short* __restrict__ P,
    float* __restrict__ out)
{
  extern __shared__ unsigned short lds[];   // 3 * LDS_TILE ushorts = 144 KB

  int bid = blockIdx.x;
  int mt = bid >> 3;          // 0..31  (linear: nt = bid%8 -> XCD affinity for B)
  int nt = bid & 7;           // 0..7
  int m0 = mt * BM, n0 = nt * BN;

  int tid  = threadIdx.x;     // 0..511
  int lane = tid & 63;
  int wid  = tid >> 6;        // 0..7
  int wr = wid >> 1, wc = wid & 1;   // 4x2 wave grid, each wave 64x64 out
  int fr = lane & 15;
  int hi = lane >> 4;                // 0..3

  // staging geometry: A-tile 32KB = 4 rounds x (512 thr x 16B); B-tile 16KB = 2 rounds
  int row0 = tid >> 3;               // 0..63 (round adds 64)
  int ch0  = tid & 7;                // 16B chunk within 128B row
  int dofs = tid * 16;               // byte offset within an 8KB round
  int sc   = (ch0 ^ (row0 & 7)) << 3;    // pre-swizzled source chunk (ushort units)

  const unsigned short* Abase = Ib   + (size_t)m0 * K3;
  const unsigned short* Bbase = Wsum + (size_t)n0 * K3;

  f32x4 acc[4][4];
  #pragma unroll
  for (int i = 0; i < 4; ++i)
    #pragma unroll
    for (int j = 0; j < 4; ++j)
      acc[i][j] = f32x4{0.f, 0.f, 0.f, 0.f};

  // stage full K-tile t (6 loads: 4 A rounds + 2 B rounds) into buffer slot.
  // LDS content: row r, chunk u holds global chunk u^(r&7) of row r (T2 both-sides).
  auto STAGE = [&](int slot, int t) {
    char* dst = (char*)(lds + slot * LDS_TILE);
    int k0 = t << 6;
    #pragma unroll
    for (int r = 0; r < 4; ++r)
      async16(Abase + (size_t)(row0 + r * 64) * K3 + k0 + sc, dst + dofs + r * 8192);
    char* dstB = dst + 2 * LDS_A;   // bytes
    #pragma unroll
    for (int r = 0; r < 2; ++r)
      async16(Bbase + (size_t)(row0 + r * 64) * K3 + k0 + sc, dstB + dofs + r * 8192);
  };

  auto MFMA16 = [&](bf16x8* a, bf16x8* b4) {
    __builtin_amdgcn_s_setprio(1);
    #pragma unroll
    for (int i = 0; i < 4; ++i)
      #pragma unroll
      for (int j = 0; j < 4; ++j)
        acc[i][j] = __builtin_amdgcn_mfma_f32_16x16x32_bf16(a[i], b4[j], acc[i][j], 0, 0, 0);
    __builtin_amdgcn_s_setprio(0);
  };

  // prologue
  STAGE(0, 0);
  STAGE(1, 1);
  asm volatile("s_waitcnt vmcnt(6)" ::: "memory");   // tile 0 landed; tile 1 in flight
  __builtin_amdgcn_s_barrier();

  #pragma unroll 1
  for (int t = 0; t < NKT; ++t) {
    const unsigned short* pA = lds + (t % 3) * LDS_TILE;
    const unsigned short* pB = pA + LDS_A;
    bool st = (t + 2) < NKT;

    bf16x8 a[2][4], b[2][4];
    // kk=0 reads FIRST (lgkmcnt(8) below relies on in-order DS retirement)
    #pragma unroll
    for (int i = 0; i < 4; ++i) {
      int R = wr * 64 + i * 16 + fr;
      a[0][i] = *(const bf16x8*)&pA[(R << 6) + (((hi) ^ (R & 7)) << 3)];
    }
    #pragma unroll
    for (int j = 0; j < 4; ++j) {
      int R = wc * 64 + j * 16 + fr;
      b[0][j] = *(const bf16x8*)&pB[(R << 6) + (((hi) ^ (R & 7)) << 3)];
    }
    __builtin_amdgcn_sched_barrier(0);     // pin: first 8 ds_reads are kk0's
    #pragma unroll
    for (int i = 0; i < 4; ++i) {
      int R = wr * 64 + i * 16 + fr;
      a[1][i] = *(const bf16x8*)&pA[(R << 6) + (((4 + hi) ^ (R & 7)) << 3)];
    }
    #pragma unroll
    for (int j = 0; j < 4; ++j) {
      int R = wc * 64 + j * 16 + fr;
      b[1][j] = *(const bf16x8*)&pB[(R << 6) + (((4 + hi) ^ (R & 7)) << 3)];
    }
    if (st) STAGE((t + 2) % 3, t + 2);
    __builtin_amdgcn_sched_barrier(0);     // pin: all reads+stage issued before waits

    asm volatile("s_waitcnt lgkmcnt(8)" ::: "memory");   // kk0 frags ready
    __builtin_amdgcn_sched_barrier(0);                    // rule #18
    MFMA16(a[0], b[0]);
    asm volatile("s_waitcnt lgkmcnt(0)" ::: "memory");   // kk1 frags ready
    __builtin_amdgcn_sched_barrier(0);
    MFMA16(a[1], b[1]);

    // end of tile: t+1 fully in LDS (its 6 are oldest), t+2's 6 stay in flight
    if (st) asm volatile("s_waitcnt vmcnt(6)" ::: "memory");
    else    asm volatile("s_waitcnt vmcnt(0)" ::: "memory");
    __builtin_amdgcn_s_barrier();
  }

  // Epilogue: C/D layout col = lane&15, row = (lane>>4)*4 + reg  [verified m89/m91]
  #pragma unroll
  for (int i = 0; i < 4; ++i) {
    #pragma unroll
    for (int j = 0; j < 4; ++j) {
      int n = n0 + wc * 64 + j * 16 + fr;
      float bs = bsum[n];
      #pragma unroll
      for (int r = 0; r < 4; ++r) {
        int m = m0 + wr * 64 + i * 16 + hi * 4 + r;
        size_t idx = (size_t)m * N_DIM + n;
        out[idx] = (acc[i][j][r] + bs) * bf2f(P[idx]);
      }
    }
  }
}

extern "C" void kernel_launch(void* const* d_in, const int* in_sizes, int n_in,
                              void* d_out, int out_size, void* d_ws, size_t ws_size,
                              hipStream_t stream) {
  const float* x = (const float*)d_in[0];
  const float* y = (const float*)d_in[1];
  const float* z = (const float*)d_in[2];
  const float* W = (const float*)d_in[3];
  const float* b = (const float*)d_in[4];
  float* out = (float*)d_out;

  // ws layout: Ib bf16 [8192*3072]; Wsum bf16 [1024*3072]; P bf16 [8192*1024]; bsum f32[1024]
  unsigned short* Ib   = (unsigned short*)d_ws;
  unsigned short* Wsum = Ib + (size_t)M_ROWS * K3;
  unsigned short* P    = Wsum + (size_t)N_DIM * K3;
  float*          bsum = (float*)(P + (size_t)M_ROWS * N_DIM);

  // 1) fused prep: convert (8192 blocks) + reduce_w (3072) + reduce_b (4)
  prep_kernel<<<11268, 256, 0, stream>>>(
      (const float4*)x, (const float4*)y, (const float4*)z, W, b,
      (ushort4*)Ib, (ushort4*)P, (ushort4*)Wsum, bsum);

  // 2) GEMM + epilogue: 32 x 8 tiles of 256x128, 144 KB dynamic LDS
  gemm_ep_kernel<<<256, 512, 3 * LDS_TILE * sizeof(unsigned short), stream>>>(
      Ib, Wsum, bsum, P, out);
}

// Round 8
// 125.820 us; speedup vs baseline: 1.6681x; 1.0993x over previous
//
#include <hip/hip_runtime.h>

// Problem constants
#define M_ROWS 8192            // B*L = 4*2048
#define N_DIM  1024            // D
#define K3     3072            // 3*D
#define KD     16              // K_DIM
#define NKT    48              // K3 / BK
#define BM     256
#define BN     128
#define BK     64
#define LDS_A  (BM * BK)       // 16384 ushorts = 32 KB
#define LDS_B  (BN * BK)       // 8192 ushorts  = 16 KB
#define LDS_TILE (LDS_A + LDS_B)  // 24576 ushorts = 48 KB; 3 buffers = 144 KB

typedef __bf16 bf16x8 __attribute__((ext_vector_type(8)));
typedef float  f32x4  __attribute__((ext_vector_type(4)));

__device__ __forceinline__ unsigned short f2bf(float f) {
  return __builtin_bit_cast(unsigned short, (__bf16)f);
}
__device__ __forceinline__ float bf2f(unsigned short u) {
  return __builtin_bit_cast(float, (unsigned int)u << 16);
}
__device__ __forceinline__ ushort4 pack4(float4 f) {
  ushort4 o; o.x = f2bf(f.x); o.y = f2bf(f.y); o.z = f2bf(f.z); o.w = f2bf(f.w);
  return o;
}

__device__ __forceinline__ void async16(const void* g, void* l) {
  __builtin_amdgcn_global_load_lds(
      (const __attribute__((address_space(1))) unsigned int*)g,
      (__attribute__((address_space(3))) unsigned int*)l, 16, 0, 0);
}

// W-side prep (runs FIRST so W's 201 MB streams through L3 before Ib/P are written):
//  blocks [0, 3072):  Wsum[d][c] = bf16(sum_k W[d*16+k][c])  (1024x3072)
//  blocks [3072, 3076): bsum[d] = sum_k b[d*16+k]  (fp32)
__global__ __launch_bounds__(256) void wsum_kernel(
    const float* __restrict__ W, const float* __restrict__ b,
    ushort4* __restrict__ Wsum4, float* __restrict__ bsum)
{
  int bid = blockIdx.x;
  int tid = threadIdx.x;
  if (bid < 3072) {
    int g  = bid * 256 + tid;            // 0 .. 786431 float4 cols
    int d  = g / 768;
    int cq = g - d * 768;
    const float4* wrow = (const float4*)(W + (size_t)d * (KD * K3));
    float sx = 0.f, sy = 0.f, sz = 0.f, sw = 0.f;
    #pragma unroll
    for (int k = 0; k < KD; ++k) {
      float4 t = wrow[(size_t)k * (K3 / 4) + cq];
      sx += t.x; sy += t.y; sz += t.z; sw += t.w;
    }
    ushort4 o; o.x = f2bf(sx); o.y = f2bf(sy); o.z = f2bf(sz); o.w = f2bf(sw);
    Wsum4[g] = o;
  } else {
    int d = (bid - 3072) * 256 + tid;
    if (d < N_DIM) {
      float s = 0.f;
      #pragma unroll
      for (int k = 0; k < KD; ++k) s += b[d * KD + k];
      bsum[d] = s;
    }
  }
}

// Input-side prep: x,y,z -> Ib[8192][3072] bf16 (cols: x|y|z) and P = bf16(x*y).
__global__ __launch_bounds__(256) void convert_kernel(
    const float4* __restrict__ x, const float4* __restrict__ y, const float4* __restrict__ z,
    ushort4* __restrict__ Ib4, ushort4* __restrict__ P4)
{
  int bid = blockIdx.x;
  int tid = threadIdx.x;
  int i = bid * 256 + tid;            // float4 index over [8192][256]
  float4 fx = x[i], fy = y[i], fz = z[i];
  size_t rb = (size_t)bid * 768;
  Ib4[rb + tid]       = pack4(fx);
  Ib4[rb + 256 + tid] = pack4(fy);
  Ib4[rb + 512 + tid] = pack4(fz);
  float4 p; p.x = fx.x * fy.x; p.y = fx.y * fy.y; p.z = fx.z * fy.z; p.w = fx.w * fy.w;
  P4[i] = pack4(p);
}

// GEMM C[m,n] = sum_k Ib[m,k]*Wsum[n,k]; out[m,n] = (C + bsum[n]) * P[m,n]
// BM=256 x BN=128, BK=64, 8 waves (4Mx2N, 64x64 each), 3-deep LDS pipeline,
// 2 phases per K-tile (m201-style interleave), counted vmcnt(6) once per K-tile,
// XOR chunk swizzle (T2), setprio around MFMA cluster (T5).  [R5 verbatim]
__global__ __launch_bounds__(512, 2) void gemm_ep_kernel(
    const unsigned short* __restrict__ Ib, const unsigned short* __restrict__ Wsum,
    const float* __restrict__ bsum, const unsigned short* __restrict__ P,
    float* __restrict__ out)
{
  extern __shared__ unsigned short lds[];   // 3 * LDS_TILE ushorts = 144 KB

  // XCD-aware bijective swizzle: 256 blocks, 8 XCDs, 32 blocks each.
  int bid = blockIdx.x;
  int swz = (bid & 7) * 32 + (bid >> 3);
  int mt = swz >> 3;          // 0..31
  int nt = swz & 7;           // 0..7
  int m0 = mt * BM, n0 = nt * BN;

  int tid  = threadIdx.x;     // 0..511
  int lane = tid & 63;
  int wid  = tid >> 6;        // 0..7
  int wr = wid >> 1, wc = wid & 1;   // 4x2 wave grid, each wave 64x64 out

  // staging geometry: A-tile 32KB = 4 rounds x (512 thr x 16B); B-tile 16KB = 2 rounds
  int row0 = tid >> 3;               // 0..63 (round adds 64)
  int ch0  = tid & 7;                // 16B chunk within 128B row
  int dofs = tid * 16;               // byte offset within an 8KB round
  int sc   = ((ch0 ^ (row0 & 7)) << 3);   // pre-swizzled source chunk (ushort units)

  const unsigned short* Abase = Ib   + (size_t)m0 * K3;
  const unsigned short* Bbase = Wsum + (size_t)n0 * K3;

  f32x4 acc[4][4];
  #pragma unroll
  for (int i = 0; i < 4; ++i)
    #pragma unroll
    for (int j = 0; j < 4; ++j)
      acc[i][j] = f32x4{0.f, 0.f, 0.f, 0.f};

  int fr = lane & 15;
  int hi = lane >> 4;                // 0..3

  auto STAGE_A = [&](int s, int t, int rlo, int rhi) {
    char* dst = (char*)(lds + s * LDS_TILE);
    int k0 = t << 6;
    for (int r = rlo; r < rhi; ++r)
      async16(Abase + (size_t)(row0 + r * 64) * K3 + k0 + sc, dst + dofs + r * 8192);
  };
  auto STAGE_B = [&](int s, int t, int rlo, int rhi) {
    char* dst = (char*)(lds + s * LDS_TILE) + 2 * LDS_A;   // bytes
    int k0 = t << 6;
    for (int r = rlo; r < rhi; ++r)
      async16(Bbase + (size_t)(row0 + r * 64) * K3 + k0 + sc, dst + dofs + r * 8192);
  };

  bf16x8 a[4], b[4];
  auto LOADAB = [&](const unsigned short* pA, const unsigned short* pB, int kk) {
    int c = (kk << 2) + hi;                 // logical chunk 0..7
    #pragma unroll
    for (int i = 0; i < 4; ++i) {
      int R = wr * 64 + i * 16 + fr;
      a[i] = *(const bf16x8*)&pA[(R << 6) + ((c ^ (R & 7)) << 3)];
    }
    #pragma unroll
    for (int j = 0; j < 4; ++j) {
      int R = wc * 64 + j * 16 + fr;
      b[j] = *(const bf16x8*)&pB[(R << 6) + ((c ^ (R & 7)) << 3)];
    }
  };
  auto MFMA16 = [&]() {
    __builtin_amdgcn_s_setprio(1);
    #pragma unroll
    for (int i = 0; i < 4; ++i)
      #pragma unroll
      for (int j = 0; j < 4; ++j)
        acc[i][j] = __builtin_amdgcn_mfma_f32_16x16x32_bf16(a[i], b[j], acc[i][j], 0, 0, 0);
    __builtin_amdgcn_s_setprio(0);
  };

  // prologue: fill tiles 0 and 1 (6 loads each)
  STAGE_A(0, 0, 0, 4); STAGE_B(0, 0, 0, 2);
  STAGE_A(1, 1, 0, 4); STAGE_B(1, 1, 0, 2);
  asm volatile("s_waitcnt vmcnt(6)" ::: "memory");   // tile 0 landed; tile 1 in flight
  __builtin_amdgcn_s_barrier();

  for (int t = 0; t < NKT; ++t) {
    const unsigned short* pA = lds + (t % 3) * LDS_TILE;
    const unsigned short* pB = pA + LDS_A;
    int s2 = (t + 2) % 3;
    bool st = (t + 2) < NKT;

    // ---- Phase 0 (kk = 0): ds_read || stage A-part || bar || MFMA || bar ----
    LOADAB(pA, pB, 0);
    if (st) STAGE_A(s2, t + 2, 0, 3);
    __builtin_amdgcn_s_barrier();
    asm volatile("s_waitcnt lgkmcnt(0)" ::: "memory");
    __builtin_amdgcn_sched_barrier(0);
    MFMA16();
    __builtin_amdgcn_s_barrier();

    // ---- Phase 1 (kk = 1): ds_read || stage rest || vmcnt || bar || MFMA || bar ----
    LOADAB(pA, pB, 1);
    if (st) { STAGE_A(s2, t + 2, 3, 4); STAGE_B(s2, t + 2, 0, 2); }
    if (st) asm volatile("s_waitcnt vmcnt(6)" ::: "memory");   // tile t+1 landed
    else    asm volatile("s_waitcnt vmcnt(0)" ::: "memory");
    __builtin_amdgcn_s_barrier();
    asm volatile("s_waitcnt lgkmcnt(0)" ::: "memory");
    __builtin_amdgcn_sched_barrier(0);
    MFMA16();
    __builtin_amdgcn_s_barrier();
  }

  // Epilogue: C/D layout col = lane&15, row = (lane>>4)*4 + reg  [verified m89/m91]
  #pragma unroll
  for (int i = 0; i < 4; ++i) {
    #pragma unroll
    for (int j = 0; j < 4; ++j) {
      int n = n0 + wc * 64 + j * 16 + fr;
      float bs = bsum[n];
      #pragma unroll
      for (int r = 0; r < 4; ++r) {
        int m = m0 + wr * 64 + i * 16 + hi * 4 + r;
        size_t idx = (size_t)m * N_DIM + n;
        out[idx] = (acc[i][j][r] + bs) * bf2f(P[idx]);
      }
    }
  }
}

extern "C" void kernel_launch(void* const* d_in, const int* in_sizes, int n_in,
                              void* d_out, int out_size, void* d_ws, size_t ws_size,
                              hipStream_t stream) {
  const float* x = (const float*)d_in[0];
  const float* y = (const float*)d_in[1];
  const float* z = (const float*)d_in[2];
  const float* W = (const float*)d_in[3];
  const float* b = (const float*)d_in[4];
  float* out = (float*)d_out;

  // ws layout: Ib bf16 [8192*3072]; Wsum bf16 [1024*3072]; P bf16 [8192*1024]; bsum f32[1024]
  unsigned short* Ib   = (unsigned short*)d_ws;
  unsigned short* Wsum = Ib + (size_t)M_ROWS * K3;
  unsigned short* P    = Wsum + (size_t)N_DIM * K3;
  float*          bsum = (float*)(P + (size_t)M_ROWS * N_DIM);

  // 1) W-side prep FIRST (its 201 MB stream won't evict Ib/P from L3)
  wsum_kernel<<<3076, 256, 0, stream>>>(W, b, (ushort4*)Wsum, bsum);

  // 2) input conversion (Ib, P land in L3 right before the GEMM reads them)
  convert_kernel<<<8192, 256, 0, stream>>>(
      (const float4*)x, (const float4*)y, (const float4*)z,
      (ushort4*)Ib, (ushort4*)P);

  // 3) GEMM + epilogue: 32 x 8 tiles of 256x128, 144 KB dynamic LDS
  gemm_ep_kernel<<<256, 512, 3 * LDS_TILE * sizeof(unsigned short), stream>>>(
      Ib, Wsum, bsum, P, out);
}

// Round 9
// 121.943 us; speedup vs baseline: 1.7211x; 1.0318x over previous
//
#include <hip/hip_runtime.h>

// Problem constants
#define M_ROWS 8192            // B*L = 4*2048
#define N_DIM  1024            // D
#define K3     3072            // 3*D
#define KD     16              // K_DIM
#define NKT    48              // K3 / BK (multiple of 3)
#define BM     256
#define BN     128
#define BK     64
#define LDS_A  (BM * BK)       // 16384 ushorts = 32 KB
#define LDS_B  (BN * BK)       // 8192 ushorts  = 16 KB
#define LDS_TILE (LDS_A + LDS_B)  // 24576 ushorts = 48 KB; 3 buffers = 144 KB

typedef __bf16 bf16x8 __attribute__((ext_vector_type(8)));
typedef float  f32x4  __attribute__((ext_vector_type(4)));

__device__ __forceinline__ unsigned short f2bf(float f) {
  return __builtin_bit_cast(unsigned short, (__bf16)f);
}
__device__ __forceinline__ float bf2f(unsigned short u) {
  return __builtin_bit_cast(float, (unsigned int)u << 16);
}
__device__ __forceinline__ ushort4 pack4(float4 f) {
  ushort4 o; o.x = f2bf(f.x); o.y = f2bf(f.y); o.z = f2bf(f.z); o.w = f2bf(f.w);
  return o;
}

__device__ __forceinline__ void async16(const void* g, void* l) {
  __builtin_amdgcn_global_load_lds(
      (const __attribute__((address_space(1))) unsigned int*)g,
      (__attribute__((address_space(3))) unsigned int*)l, 16, 0, 0);
}

// W-side prep (runs FIRST so W's 201 MB streams through L3 before Ib/P are written)
__global__ __launch_bounds__(256) void wsum_kernel(
    const float* __restrict__ W, const float* __restrict__ b,
    ushort4* __restrict__ Wsum4, float* __restrict__ bsum)
{
  int bid = blockIdx.x;
  int tid = threadIdx.x;
  if (bid < 3072) {
    int g  = bid * 256 + tid;            // 0 .. 786431 float4 cols
    int d  = g / 768;
    int cq = g - d * 768;
    const float4* wrow = (const float4*)(W + (size_t)d * (KD * K3));
    float sx = 0.f, sy = 0.f, sz = 0.f, sw = 0.f;
    #pragma unroll
    for (int k = 0; k < KD; ++k) {
      float4 t = wrow[(size_t)k * (K3 / 4) + cq];
      sx += t.x; sy += t.y; sz += t.z; sw += t.w;
    }
    ushort4 o; o.x = f2bf(sx); o.y = f2bf(sy); o.z = f2bf(sz); o.w = f2bf(sw);
    Wsum4[g] = o;
  } else {
    int d = (bid - 3072) * 256 + tid;
    if (d < N_DIM) {
      float s = 0.f;
      #pragma unroll
      for (int k = 0; k < KD; ++k) s += b[d * KD + k];
      bsum[d] = s;
    }
  }
}

// Input-side prep: x,y,z -> Ib[8192][3072] bf16 (cols: x|y|z) and P = bf16(x*y).
__global__ __launch_bounds__(256) void convert_kernel(
    const float4* __restrict__ x, const float4* __restrict__ y, const float4* __restrict__ z,
    ushort4* __restrict__ Ib4, ushort4* __restrict__ P4)
{
  int bid = blockIdx.x;
  int tid = threadIdx.x;
  int i = bid * 256 + tid;            // float4 index over [8192][256]
  float4 fx = x[i], fy = y[i], fz = z[i];
  size_t rb = (size_t)bid * 768;
  Ib4[rb + tid]       = pack4(fx);
  Ib4[rb + 256 + tid] = pack4(fy);
  Ib4[rb + 512 + tid] = pack4(fz);
  float4 p; p.x = fx.x * fy.x; p.y = fx.y * fy.y; p.z = fx.z * fy.z; p.w = fx.w * fy.w;
  P4[i] = pack4(p);
}

// GEMM C[m,n] = sum_k Ib[m,k]*Wsum[n,k]; out[m,n] = (C + bsum[n]) * P[m,n]
// BM=256 x BN=128, BK=64, 8 waves (4Mx2N, 64x64 each), 3-deep LDS pipeline.
// Fragment-software-pipelined: each phase issues the NEXT phase's 8 ds_reads,
// waits lgkmcnt(8) (counted, not drain), MFMAs the previous phase's fragments.
// 2 barriers per K-tile, vmcnt(6) counted once per K-tile.
__global__ __launch_bounds__(512, 2) void gemm_ep_kernel(
    const unsigned short* __restrict__ Ib, const unsigned short* __restrict__ Wsum,
    const float* __restrict__ bsum, const unsigned short* __restrict__ P,
    float* __restrict__ out)
{
  extern __shared__ unsigned short lds[];   // 3 * LDS_TILE ushorts = 144 KB

  // XCD-aware bijective swizzle: 256 blocks, 8 XCDs, 32 blocks each.
  int bid = blockIdx.x;
  int swz = (bid & 7) * 32 + (bid >> 3);
  int mt = swz >> 3;          // 0..31
  int nt = swz & 7;           // 0..7
  int m0 = mt * BM, n0 = nt * BN;

  int tid  = threadIdx.x;     // 0..511
  int lane = tid & 63;
  int wid  = tid >> 6;        // 0..7
  int wr = wid >> 1, wc = wid & 1;   // 4x2 wave grid, each wave 64x64 out
  int fr = lane & 15;
  int hi = lane >> 4;                // 0..3

  // staging geometry: A-tile 32KB = 4 rounds x (512 thr x 16B); B-tile 16KB = 2 rounds
  int row0 = tid >> 3;               // 0..63 (round adds 64)
  int ch0  = tid & 7;                // 16B chunk within 128B row
  int dofs = tid * 16;               // byte offset within an 8KB round
  int sc   = (ch0 ^ (row0 & 7)) << 3;    // pre-swizzled source chunk (ushort units)

  const unsigned short* Abase = Ib   + (size_t)m0 * K3;
  const unsigned short* Bbase = Wsum + (size_t)n0 * K3;

  f32x4 acc[4][4];
  #pragma unroll
  for (int i = 0; i < 4; ++i)
    #pragma unroll
    for (int j = 0; j < 4; ++j)
      acc[i][j] = f32x4{0.f, 0.f, 0.f, 0.f};

  // stage full K-tile t (6 loads: 4 A rounds + 2 B rounds) into buffer slot.
  // LDS content: row r, chunk u holds global chunk u^(r&7) of row r (T2 both-sides).
  auto STAGE = [&](int slot, int t) {
    char* dst = (char*)(lds + slot * LDS_TILE);
    int k0 = t << 6;
    #pragma unroll
    for (int r = 0; r < 4; ++r)
      async16(Abase + (size_t)(row0 + r * 64) * K3 + k0 + sc, dst + dofs + r * 8192);
    char* dstB = dst + 2 * LDS_A;   // bytes
    #pragma unroll
    for (int r = 0; r < 2; ++r)
      async16(Bbase + (size_t)(row0 + r * 64) * K3 + k0 + sc, dstB + dofs + r * 8192);
  };

  // 8 ds_read_b128: fragments for sub-k kk from a tile slot
  auto LOAD8 = [&](const unsigned short* pA, int kk, bf16x8 (&a)[4], bf16x8 (&b)[4]) {
    const unsigned short* pB = pA + LDS_A;
    int c = (kk << 2) + hi;                 // logical chunk 0..7
    #pragma unroll
    for (int i = 0; i < 4; ++i) {
      int R = wr * 64 + i * 16 + fr;
      a[i] = *(const bf16x8*)&pA[(R << 6) + ((c ^ (R & 7)) << 3)];
    }
    #pragma unroll
    for (int j = 0; j < 4; ++j) {
      int R = wc * 64 + j * 16 + fr;
      b[j] = *(const bf16x8*)&pB[(R << 6) + ((c ^ (R & 7)) << 3)];
    }
  };
  auto MFMA16 = [&](bf16x8 (&a)[4], bf16x8 (&b)[4]) {
    __builtin_amdgcn_s_setprio(1);
    #pragma unroll
    for (int i = 0; i < 4; ++i)
      #pragma unroll
      for (int j = 0; j < 4; ++j)
        acc[i][j] = __builtin_amdgcn_mfma_f32_16x16x32_bf16(a[i], b[j], acc[i][j], 0, 0, 0);
    __builtin_amdgcn_s_setprio(0);
  };

  bf16x8 aA[4], bA[4], aB[4], bB[4];   // double-buffered fragment sets

  // One K-tile: enter with {aA,bA} = frags(t,kk0) pending-or-ready (reads issued).
  //   kk0 phase: read frags(t,kk1)->B | stage t+2 | vmcnt(6) | lgkm(8) | MFMA(A) | bar
  //   kk1 phase: read frags(t+1,kk0)->A |                     lgkm(8) | MFMA(B) | bar
  auto TILE = [&](int t, const unsigned short* pCur, const unsigned short* pNext,
                  int stSlot) {
    bool st = (t + 2) < NKT;
    // ---- phase kk0 ----
    LOAD8(pCur, 1, aB, bB);
    __builtin_amdgcn_sched_barrier(0);          // keep the 8-read group intact
    if (st) {
      STAGE(stSlot, t + 2);
      asm volatile("s_waitcnt vmcnt(6)" ::: "memory");   // tile t+1 landed
    } else {
      asm volatile("s_waitcnt vmcnt(0)" ::: "memory");
    }
    asm volatile("s_waitcnt lgkmcnt(8)" ::: "memory");   // frags(t,kk0) ready
    __builtin_amdgcn_sched_barrier(0);                    // rule #18
    MFMA16(aA, bA);
    __builtin_amdgcn_s_barrier();
    // ---- phase kk1 ----
    LOAD8(pNext, 0, aA, bA);                    // frags(t+1,kk0); safe after bar
    __builtin_amdgcn_sched_barrier(0);
    asm volatile("s_waitcnt lgkmcnt(8)" ::: "memory");   // frags(t,kk1) ready
    __builtin_amdgcn_sched_barrier(0);
    MFMA16(aB, bB);
    __builtin_amdgcn_s_barrier();
  };

  const unsigned short* s0 = lds;
  const unsigned short* s1 = lds + LDS_TILE;
  const unsigned short* s2 = lds + 2 * LDS_TILE;

  // prologue: stage tiles 0,1; then issue frags(0,kk0)
  STAGE(0, 0);
  STAGE(1, 1);
  asm volatile("s_waitcnt vmcnt(6)" ::: "memory");   // tile 0 landed; tile 1 in flight
  __builtin_amdgcn_s_barrier();
  LOAD8(s0, 0, aA, bA);
  __builtin_amdgcn_sched_barrier(0);

  #pragma unroll 1
  for (int t = 0; t < NKT; t += 3) {
    TILE(t,     s0, s1, 2);
    TILE(t + 1, s1, s2, 0);
    TILE(t + 2, s2, s0, 1);
  }

  // Epilogue: C/D layout col = lane&15, row = (lane>>4)*4 + reg  [verified m89/m91]
  #pragma unroll
  for (int i = 0; i < 4; ++i) {
    #pragma unroll
    for (int j = 0; j < 4; ++j) {
      int n = n0 + wc * 64 + j * 16 + fr;
      float bs = bsum[n];
      #pragma unroll
      for (int r = 0; r < 4; ++r) {
        int m = m0 + wr * 64 + i * 16 + hi * 4 + r;
        size_t idx = (size_t)m * N_DIM + n;
        out[idx] = (acc[i][j][r] + bs) * bf2f(P[idx]);
      }
    }
  }
}

extern "C" void kernel_launch(void* const* d_in, const int* in_sizes, int n_in,
                              void* d_out, int out_size, void* d_ws, size_t ws_size,
                              hipStream_t stream) {
  const float* x = (const float*)d_in[0];
  const float* y = (const float*)d_in[1];
  const float* z = (const float*)d_in[2];
  const float* W = (const float*)d_in[3];
  const float* b = (const float*)d_in[4];
  float* out = (float*)d_out;

  // ws layout: Ib bf16 [8192*3072]; Wsum bf16 [1024*3072]; P bf16 [8192*1024]; bsum f32[1024]
  unsigned short* Ib   = (unsigned short*)d_ws;
  unsigned short* Wsum = Ib + (size_t)M_ROWS * K3;
  unsigned short* P    = Wsum + (size_t)N_DIM * K3;
  float*          bsum = (float*)(P + (size_t)M_ROWS * N_DIM);

  // 1) W-side prep FIRST (its 201 MB stream won't evict Ib/P from L3)
  wsum_kernel<<<3076, 256, 0, stream>>>(W, b, (ushort4*)Wsum, bsum);

  // 2) input conversion (Ib, P land in L3 right before the GEMM reads them)
  convert_kernel<<<8192, 256, 0, stream>>>(
      (const float4*)x, (const float4*)y, (const float4*)z,
      (ushort4*)Ib, (ushort4*)P);

  // 3) GEMM + epilogue: 32 x 8 tiles of 256x128, 144 KB dynamic LDS
  gemm_ep_kernel<<<256, 512, 3 * LDS_TILE * sizeof(unsigned short), stream>>>(
      Ib, Wsum, bsum, P, out);
}